// Round 4
// baseline (234.981 us; speedup 1.0000x reference)
//
#include <hip/hip_runtime.h>
#include <hip/hip_bf16.h>

// B=4, S=2048, D=1024, E=8, H=512, top-2 + shared expert
#define TOKENS 8192
#define D_DIM  1024
#define E_NUM  8
#define H_DIM  512
#define N1     4608            // E*H + H (Bt1 rows)
#define CAP    3072            // per-expert row capacity (~2048 expected, +26 sigma)
#define ETILES (CAP / 128)     // 24 tiles per expert segment
#define EXP_ROWS (E_NUM * CAP) // 24576 expert rows
#define SH_BASE  EXP_ROWS      // shared segment base in Hs row space
#define HS_ROWS (EXP_ROWS + TOKENS)  // 32768

typedef __bf16 bf16_t;
typedef __bf16 bf16x8 __attribute__((ext_vector_type(8)));
typedef __bf16 bf16x4 __attribute__((ext_vector_type(4)));
typedef float  f32x4  __attribute__((ext_vector_type(4)));

// tanh-form GELU, 7 VALU ops: gelu(v) = v * (1 - 1/(exp2(v*(A + B*v^2)) + 1))
// A = 0.7978845608*2/ln2 ... folded: z = 2*0.7978845608*log2(e)*v*(1+0.044715 v^2)
__device__ __forceinline__ float gelu_fast(float v) {
  float w = v * v;
  float t = __builtin_fmaf(w, 0.10294307f, 2.30258835f);  // 2*0.7978845608*log2e*(0.044715), same*1
  float z = v * t;
  float e = __builtin_amdgcn_exp2f(z);
  float r = __builtin_amdgcn_rcpf(e + 1.0f);
  return v - v * r;
}

// ---------------------------------------------------------------- routing (+ fused x->bf16 cast)
// one wave per token; fp64 accumulation so top-2 selection matches numpy ref.
// writes gateT[e][tok] (dense, coalesced for listbuild) and sel[tok]=i1*8+i2.
__global__ __launch_bounds__(256) void routing_kernel(
    const float* __restrict__ x, const float* __restrict__ gW,
    const float* __restrict__ route_scale, float* __restrict__ gateT,
    int* __restrict__ sel, bf16_t* __restrict__ Xb) {
  int tok  = blockIdx.x * 4 + (threadIdx.x >> 6);
  int lane = threadIdx.x & 63;
  const float* xr = x + (size_t)tok * D_DIM;
  double p[E_NUM];
#pragma unroll
  for (int e = 0; e < E_NUM; ++e) p[e] = 0.0;
  for (int d = lane; d < D_DIM; d += 64) {
    double xv = (double)xr[d];
    const float* g = gW + (size_t)d * E_NUM;
#pragma unroll
    for (int e = 0; e < E_NUM; ++e) p[e] += xv * (double)g[e];
  }
#pragma unroll
  for (int off = 32; off > 0; off >>= 1) {
#pragma unroll
    for (int e = 0; e < E_NUM; ++e) p[e] += __shfl_xor(p[e], off, 64);
  }
  if (lane == 0) {
    double rs = (double)route_scale[0];
    double s[E_NUM];
#pragma unroll
    for (int e = 0; e < E_NUM; ++e) s[e] = rs / (1.0 + exp(-p[e]));
    int i1 = 0;
#pragma unroll
    for (int e = 1; e < E_NUM; ++e) if (s[e] > s[i1]) i1 = e;
    int i2 = (i1 == 0) ? 1 : 0;
#pragma unroll
    for (int e = 0; e < E_NUM; ++e) if (e != i1 && s[e] > s[i2]) i2 = e;
    double inv = 1.0 / (s[i1] + s[i2]);
    float o[E_NUM];
#pragma unroll
    for (int e = 0; e < E_NUM; ++e) o[e] = 0.f;
    o[i1] = (float)(s[i1] * inv);
    o[i2] = (float)(s[i2] * inv);
#pragma unroll
    for (int e = 0; e < E_NUM; ++e) gateT[(size_t)e * TOKENS + tok] = o[e];
    sel[tok] = i1 * 8 + i2;
  }
  // fused cast of this token's row to bf16
  const float4* x4 = (const float4*)xr;
  bf16x4* xb4 = (bf16x4*)(Xb + (size_t)tok * D_DIM);
#pragma unroll
  for (int i = 0; i < 4; ++i) {
    float4 v = x4[i * 64 + lane];
    bf16x4 o = { (bf16_t)v.x, (bf16_t)v.y, (bf16_t)v.z, (bf16_t)v.w };
    xb4[i * 64 + lane] = o;
  }
}

// ------------------------------------------------- Bt1 (N1 x 1024): row n=e*512+h holds W1[e][:,h]; rows 4096+ = Ws1^T
__global__ __launch_bounds__(256) void repack1_kernel(
    const float* __restrict__ W1, const float* __restrict__ Ws1,
    bf16_t* __restrict__ Bt1) {
  __shared__ float tile[32][33];
  int k0 = blockIdx.x * 32, n0 = blockIdx.y * 32;
  int tx = threadIdx.x, ty = threadIdx.y;
#pragma unroll
  for (int i = 0; i < 4; ++i) {
    int kl = ty + i * 8;
    int n = n0 + tx, k = k0 + kl;
    float v;
    if (n0 < 4096) v = W1[(size_t)(n >> 9) * (D_DIM * H_DIM) + (size_t)k * H_DIM + (n & 511)];
    else           v = Ws1[(size_t)k * H_DIM + (n - 4096)];
    tile[kl][tx] = v;
  }
  __syncthreads();
#pragma unroll
  for (int i = 0; i < 4; ++i) {
    int nl = ty + i * 8;
    Bt1[(size_t)(n0 + nl) * D_DIM + k0 + tx] = (bf16_t)tile[tx][nl];
  }
}

// ------------------------------------------------- Bt2e[e][d][h]: per-expert W2[e]^T (e=8 -> Ws2^T)
__global__ __launch_bounds__(256) void repack2e_kernel(
    const float* __restrict__ W2, const float* __restrict__ Ws2,
    bf16_t* __restrict__ Bt2e) {
  __shared__ float tile[32][33];
  int d0 = blockIdx.x * 32, h0 = blockIdx.y * 32, e = blockIdx.z;
  int tx = threadIdx.x, ty = threadIdx.y;
#pragma unroll
  for (int i = 0; i < 4; ++i) {
    int hl = ty + i * 8;
    int h = h0 + hl, d = d0 + tx;
    float v = (e < E_NUM) ? W2[((size_t)e * H_DIM + h) * D_DIM + d]
                          : Ws2[(size_t)h * D_DIM + d];
    tile[hl][tx] = v;
  }
  __syncthreads();
#pragma unroll
  for (int i = 0; i < 4; ++i) {
    int dl = ty + i * 8;
    Bt2e[((size_t)e * D_DIM + (d0 + dl)) * H_DIM + h0 + tx] = (bf16_t)tile[tx][dl];
  }
}

// ---------------------------------------------------------------- list build: 1 block, 8 waves (wave = expert), no barriers
__global__ __launch_bounds__(512) void listbuild_kernel(
    const float* __restrict__ gateT, const int* __restrict__ sel,
    int* __restrict__ perm, float* __restrict__ grow,
    int* __restrict__ tok2row, int* __restrict__ padcnt) {
  const int e = threadIdx.x >> 6, lane = threadIdx.x & 63;
  const float* row = gateT + (size_t)e * TOKENS;
  const int base = e * CAP;
  int running = 0;
  for (int c = 0; c < TOKENS / 64; ++c) {
    int tok = c * 64 + lane;
    float gv = row[tok];
    bool f = gv > 0.f;
    unsigned long long m = __ballot(f);
    if (f) {
      int idx = running + __popcll(m & ((1ull << lane) - 1ull));
      if (idx < CAP) {
        perm[base + idx] = tok;
        grow[base + idx] = gv;
        int s = sel[tok];
        int other = ((s >> 3) == e) ? (s & 7) : (s >> 3);
        tok2row[tok * 2 + (e > other ? 1 : 0)] = base + idx;
      }
    }
    running += __popcll(m);
  }
  if (running > CAP) running = CAP;
  int pc = (running + 127) & ~127;
  for (int i = running + lane; i < pc; i += 64) { perm[base + i] = 0; grow[base + i] = 0.f; }
  if (lane == 0) padcnt[e] = pc;
}

// ---------------------------------------------------------------- 3-buffer single-barrier GEMM core
// 128x128 tile, BK=32, 4 waves 2x2, 16x16x32 MFMA. One s_barrier per K-step,
// counted vmcnt(4) (never 0 mid-loop). Barrier-per-iter bounds wave skew to 1,
// so staging buf (k+1)%3 never collides with readers of (k-1)%3.
__device__ __forceinline__ void gemm_core(
    const char* ga0, const char* ga1, const char* gb0, const char* gb1,
    int kiters, bf16_t* sA, bf16_t* sB, int wave, int lane, int wr, int wc,
    f32x4 (&acc)[4][4]) {
  const int kb = (lane >> 4) * 16;
  const int ar = wr * 64 + (lane & 15);
  const int br = wc * 64 + (lane & 15);
  auto stage = [&](int buf, int kk) {
    const size_t ko = (size_t)kk * 64;
    char* la = (char*)sA + buf * 8192 + wave * 1024;
    char* lb = (char*)sB + buf * 8192 + wave * 1024;
    __builtin_amdgcn_global_load_lds(
        (const __attribute__((address_space(1))) void*)(ga0 + ko),
        (__attribute__((address_space(3))) void*)la, 16, 0, 0);
    __builtin_amdgcn_global_load_lds(
        (const __attribute__((address_space(1))) void*)(ga1 + ko),
        (__attribute__((address_space(3))) void*)(la + 4096), 16, 0, 0);
    __builtin_amdgcn_global_load_lds(
        (const __attribute__((address_space(1))) void*)(gb0 + ko),
        (__attribute__((address_space(3))) void*)lb, 16, 0, 0);
    __builtin_amdgcn_global_load_lds(
        (const __attribute__((address_space(1))) void*)(gb1 + ko),
        (__attribute__((address_space(3))) void*)(lb + 4096), 16, 0, 0);
  };
  stage(0, 0);
  int nb = 1;   // buffer index of tile kk+1
  for (int kk = 0; kk < kiters; ++kk) {
    if (kk + 1 < kiters) {
      stage(nb, kk + 1);
      asm volatile("s_waitcnt vmcnt(4)" ::: "memory");  // tile kk fully landed
    } else {
      asm volatile("s_waitcnt vmcnt(0)" ::: "memory");
    }
    __builtin_amdgcn_s_barrier();
    asm volatile("" ::: "memory");
    const int cur = (nb == 0) ? 2 : nb - 1;            // kk % 3
    const char* bA = (const char*)sA + cur * 8192;
    const char* bB = (const char*)sB + cur * 8192;
    bf16x8 af[4], bfv[4];
#pragma unroll
    for (int m = 0; m < 4; ++m)
      af[m] = *(const bf16x8*)(bA + (size_t)(ar + m * 16) * 64 + kb);
#pragma unroll
    for (int n = 0; n < 4; ++n)
      bfv[n] = *(const bf16x8*)(bB + (size_t)(br + n * 16) * 64 + kb);
#pragma unroll
    for (int m = 0; m < 4; ++m)
#pragma unroll
      for (int n = 0; n < 4; ++n)
        acc[m][n] = __builtin_amdgcn_mfma_f32_16x16x32_bf16(af[m], bfv[n], acc[m][n], 0, 0, 0);
    asm volatile("" ::: "memory");   // next iter's stage stays below this point
    nb = (nb == 2) ? 0 : nb + 1;
  }
}

// ---------------------------------------------------------------- GEMM1: Hs = gate * gelu(X[perm] @ W1[e]^T + b1)
__global__ __launch_bounds__(256) void gemm1e_kernel(
    const bf16_t* __restrict__ Xb, const bf16_t* __restrict__ Bt1,
    const int* __restrict__ perm, const float* __restrict__ grow,
    const int* __restrict__ padcnt,
    const float* __restrict__ b1, const float* __restrict__ bs1,
    bf16_t* __restrict__ Hs) {
  __shared__ bf16_t sA[3 * 128 * 32];
  __shared__ bf16_t sB[3 * 128 * 32];
  const int y = blockIdx.y;
  const int t = threadIdx.x, wave = t >> 6, lane = t & 63, wr = wave >> 1, wc = wave & 1;
  const int n0 = blockIdx.x * 128;   // N = 512
  const int r = t >> 2, cb = (t & 3) * 16;
  int e, rowbase, tok0, tok1;
  if (y < E_NUM * ETILES) {
    e = y / ETILES;
    const int lt = y - e * ETILES;
    if (lt * 128 >= padcnt[e]) return;
    rowbase = e * CAP + lt * 128;
    tok0 = perm[rowbase + r];
    tok1 = perm[rowbase + 64 + r];
  } else {
    e = E_NUM;
    const int st = y - E_NUM * ETILES;
    rowbase = SH_BASE + st * 128;
    tok0 = st * 128 + r;
    tok1 = st * 128 + 64 + r;
  }
  const char* ga0 = (const char*)Xb + (size_t)tok0 * 2048 + cb;
  const char* ga1 = (const char*)Xb + (size_t)tok1 * 2048 + cb;
  const bf16_t* W = Bt1 + (size_t)e * H_DIM * D_DIM;
  const char* gb0 = (const char*)W + (size_t)(n0 + r) * 2048 + cb;
  const char* gb1 = (const char*)W + (size_t)(n0 + 64 + r) * 2048 + cb;
  f32x4 acc[4][4];
#pragma unroll
  for (int i = 0; i < 4; ++i)
#pragma unroll
    for (int j = 0; j < 4; ++j) acc[i][j] = (f32x4){0.f, 0.f, 0.f, 0.f};
  gemm_core(ga0, ga1, gb0, gb1, D_DIM / 32, sA, sB, wave, lane, wr, wc, acc);

  const float* bias = (e < E_NUM) ? (b1 + e * H_DIM) : bs1;
#pragma unroll
  for (int m = 0; m < 4; ++m) {
    const int rloc = wr * 64 + m * 16 + (lane >> 4) * 4;
    float gr[4];
#pragma unroll
    for (int q = 0; q < 4; ++q)
      gr[q] = (e < E_NUM) ? grow[rowbase + rloc + q] : 1.0f;
#pragma unroll
    for (int n = 0; n < 4; ++n) {
      const int col = n0 + wc * 64 + n * 16 + (lane & 15);
      const float bv = bias[col];
#pragma unroll
      for (int q = 0; q < 4; ++q) {
        float v = gelu_fast(acc[m][n][q] + bv);
        Hs[(size_t)(rowbase + rloc + q) * H_DIM + col] = (bf16_t)(v * gr[q]);
      }
    }
  }
}

// ---------------------------------------------------------------- GEMM2 expert tiles: Ys(bf16) = acc + grow*b2[e]
__global__ __launch_bounds__(256) void gemm2e_kernel(
    const bf16_t* __restrict__ Hs, const bf16_t* __restrict__ Bt2e,
    const float* __restrict__ grow, const int* __restrict__ padcnt,
    const float* __restrict__ b2, bf16_t* __restrict__ Ys) {
  __shared__ bf16_t sA[3 * 128 * 32];
  __shared__ bf16_t sB[3 * 128 * 32];
  const int y = blockIdx.y;
  const int e = y / ETILES;
  const int lt = y - e * ETILES;
  if (lt * 128 >= padcnt[e]) return;
  const int rowbase = e * CAP + lt * 128;
  const int t = threadIdx.x, wave = t >> 6, lane = t & 63, wr = wave >> 1, wc = wave & 1;
  const int n0 = blockIdx.x * 128;   // N = 1024
  const int r = t >> 2, cb = (t & 3) * 16;
  const char* ga0 = (const char*)Hs + (size_t)(rowbase + r) * 1024 + cb;
  const char* ga1 = (const char*)Hs + (size_t)(rowbase + 64 + r) * 1024 + cb;
  const bf16_t* W = Bt2e + (size_t)e * D_DIM * H_DIM;
  const char* gb0 = (const char*)W + (size_t)(n0 + r) * 1024 + cb;
  const char* gb1 = (const char*)W + (size_t)(n0 + 64 + r) * 1024 + cb;
  f32x4 acc[4][4];
#pragma unroll
  for (int i = 0; i < 4; ++i)
#pragma unroll
    for (int j = 0; j < 4; ++j) acc[i][j] = (f32x4){0.f, 0.f, 0.f, 0.f};
  gemm_core(ga0, ga1, gb0, gb1, H_DIM / 32, sA, sB, wave, lane, wr, wc, acc);

  const float* bb = b2 + (size_t)e * D_DIM;
#pragma unroll
  for (int m = 0; m < 4; ++m) {
    const int rloc = wr * 64 + m * 16 + (lane >> 4) * 4;
    float gr[4];
#pragma unroll
    for (int q = 0; q < 4; ++q) gr[q] = grow[rowbase + rloc + q];
#pragma unroll
    for (int n = 0; n < 4; ++n) {
      const int col = n0 + wc * 64 + n * 16 + (lane & 15);
      const float bv = bb[col];
#pragma unroll
      for (int q = 0; q < 4; ++q)
        Ys[(size_t)(rowbase + rloc + q) * D_DIM + col] = (bf16_t)(acc[m][n][q] + gr[q] * bv);
    }
  }
}

// ---------------------------------------------------------------- GEMM2 shared tiles + combine:
// out[tok] = acc + bs2 + Ys[r0(tok)] + Ys[r1(tok)]
__global__ __launch_bounds__(256) void gemm2s_kernel(
    const bf16_t* __restrict__ Hs, const bf16_t* __restrict__ Bt2e,
    const int* __restrict__ tok2row, const float* __restrict__ bs2,
    const bf16_t* __restrict__ Ys, float* __restrict__ out) {
  __shared__ bf16_t sA[3 * 128 * 32];
  __shared__ bf16_t sB[3 * 128 * 32];
  const int tokbase = blockIdx.y * 128;
  const int rowbase = SH_BASE + tokbase;
  const int t = threadIdx.x, wave = t >> 6, lane = t & 63, wr = wave >> 1, wc = wave & 1;
  const int n0 = blockIdx.x * 128;   // N = 1024
  const int r = t >> 2, cb = (t & 3) * 16;
  const char* ga0 = (const char*)Hs + (size_t)(rowbase + r) * 1024 + cb;
  const char* ga1 = (const char*)Hs + (size_t)(rowbase + 64 + r) * 1024 + cb;
  const bf16_t* W = Bt2e + (size_t)E_NUM * D_DIM * H_DIM;
  const char* gb0 = (const char*)W + (size_t)(n0 + r) * 1024 + cb;
  const char* gb1 = (const char*)W + (size_t)(n0 + 64 + r) * 1024 + cb;
  f32x4 acc[4][4];
#pragma unroll
  for (int i = 0; i < 4; ++i)
#pragma unroll
    for (int j = 0; j < 4; ++j) acc[i][j] = (f32x4){0.f, 0.f, 0.f, 0.f};
  gemm_core(ga0, ga1, gb0, gb1, H_DIM / 32, sA, sB, wave, lane, wr, wc, acc);

#pragma unroll
  for (int m = 0; m < 4; ++m) {
    const int rloc = wr * 64 + m * 16 + (lane >> 4) * 4;
    int r0[4], r1[4];
#pragma unroll
    for (int q = 0; q < 4; ++q) {
      const int tok = tokbase + rloc + q;
      r0[q] = tok2row[tok * 2];
      r1[q] = tok2row[tok * 2 + 1];
    }
#pragma unroll
    for (int n = 0; n < 4; ++n) {
      const int col = n0 + wc * 64 + n * 16 + (lane & 15);
      const float bv = bs2[col];
#pragma unroll
      for (int q = 0; q < 4; ++q) {
        const int tok = tokbase + rloc + q;
        float y0 = (float)Ys[(size_t)r0[q] * D_DIM + col];
        float y1 = (float)Ys[(size_t)r1[q] * D_DIM + col];
        out[(size_t)tok * D_DIM + col] = acc[m][n][q] + bv + y0 + y1;
      }
    }
  }
}

// ---------------------------------------------------------------- launch
extern "C" void kernel_launch(void* const* d_in, const int* in_sizes, int n_in,
                              void* d_out, int out_size, void* d_ws, size_t ws_size,
                              hipStream_t stream) {
  (void)in_sizes; (void)n_in; (void)out_size; (void)ws_size;
  const float* x    = (const float*)d_in[0];
  const float* gW   = (const float*)d_in[1];
  const float* W1   = (const float*)d_in[2];
  const float* b1   = (const float*)d_in[3];
  const float* W2   = (const float*)d_in[4];
  const float* b2   = (const float*)d_in[5];
  const float* Ws1  = (const float*)d_in[6];
  const float* bs1  = (const float*)d_in[7];
  const float* Ws2  = (const float*)d_in[8];
  const float* bs2  = (const float*)d_in[9];
  const float* rsc  = (const float*)d_in[10];
  float* out = (float*)d_out;

  char* w = (char*)d_ws;
  float*  gateT = (float*)w;  w += (size_t)E_NUM * TOKENS * 4;       // 0.25 MB
  int*    sel   = (int*)w;    w += (size_t)TOKENS * 4;               // 32 KB
  bf16_t* Xb    = (bf16_t*)w; w += (size_t)TOKENS * D_DIM * 2;       // 16.8 MB
  bf16_t* Bt1   = (bf16_t*)w; w += (size_t)N1 * D_DIM * 2;           // 9.4 MB
  bf16_t* Bt2e  = (bf16_t*)w; w += (size_t)9 * D_DIM * H_DIM * 2;    // 9.4 MB
  bf16_t* Hs    = (bf16_t*)w; w += (size_t)HS_ROWS * H_DIM * 2;      // 33.6 MB
  bf16_t* Ys    = (bf16_t*)w; w += (size_t)EXP_ROWS * D_DIM * 2;     // 50.3 MB
  int*    perm  = (int*)w;    w += (size_t)EXP_ROWS * 4;             // 98 KB
  float*  grow  = (float*)w;  w += (size_t)EXP_ROWS * 4;             // 98 KB
  int*    tok2row = (int*)w;  w += (size_t)TOKENS * 2 * 4;           // 64 KB
  int*    padcnt  = (int*)w;                                         // 32 B

  routing_kernel<<<TOKENS / 4, 256, 0, stream>>>(x, gW, rsc, gateT, sel, Xb);
  repack1_kernel<<<dim3(D_DIM / 32, N1 / 32), dim3(32, 8), 0, stream>>>(W1, Ws1, Bt1);
  repack2e_kernel<<<dim3(D_DIM / 32, H_DIM / 32, 9), dim3(32, 8), 0, stream>>>(W2, Ws2, Bt2e);
  listbuild_kernel<<<1, 512, 0, stream>>>(gateT, sel, perm, grow, tok2row, padcnt);

  gemm1e_kernel<<<dim3(H_DIM / 128, E_NUM * ETILES + TOKENS / 128), 256, 0, stream>>>(
      Xb, Bt1, perm, grow, padcnt, b1, bs1, Hs);
  gemm2e_kernel<<<dim3(D_DIM / 128, E_NUM * ETILES), 256, 0, stream>>>(
      Hs, Bt2e, grow, padcnt, b2, Ys);
  gemm2s_kernel<<<dim3(D_DIM / 128, TOKENS / 128), 256, 0, stream>>>(
      Hs, Bt2e, tok2row, bs2, Ys, out);
}

// Round 5
// 183.395 us; speedup vs baseline: 1.2813x; 1.2813x over previous
//
#include <hip/hip_runtime.h>
#include <hip/hip_bf16.h>

// B=4, S=2048, D=1024, E=8, H=512, top-2 + shared expert
#define TOKENS 8192
#define D_DIM  1024
#define E_NUM  8
#define H_DIM  512
#define N1     4608            // E*H + H (Bt1 rows)
#define CAP    3072            // per-expert row capacity (~2048 expected, +26 sigma)
#define ETILES (CAP / 128)     // 24 tiles per expert segment
#define EXP_ROWS (E_NUM * CAP) // 24576 expert rows
#define SH_BASE  EXP_ROWS      // shared segment base in Hs row space
#define HS_ROWS (EXP_ROWS + TOKENS)  // 32768

typedef __bf16 bf16_t;
typedef __bf16 bf16x8 __attribute__((ext_vector_type(8)));
typedef __bf16 bf16x4 __attribute__((ext_vector_type(4)));
typedef float  f32x4  __attribute__((ext_vector_type(4)));

// tanh-form GELU, 7 VALU ops
__device__ __forceinline__ float gelu_fast(float v) {
  float w = v * v;
  float t = __builtin_fmaf(w, 0.10294307f, 2.30258835f);
  float z = v * t;
  float e = __builtin_amdgcn_exp2f(z);
  float r = __builtin_amdgcn_rcpf(e + 1.0f);
  return v - v * r;
}

// ---------------------------------------------------------------- routing (+ fused x->bf16 cast)
__global__ __launch_bounds__(256) void routing_kernel(
    const float* __restrict__ x, const float* __restrict__ gW,
    const float* __restrict__ route_scale, float* __restrict__ gateT,
    int* __restrict__ sel, bf16_t* __restrict__ Xb) {
  int tok  = blockIdx.x * 4 + (threadIdx.x >> 6);
  int lane = threadIdx.x & 63;
  const float* xr = x + (size_t)tok * D_DIM;
  double p[E_NUM];
#pragma unroll
  for (int e = 0; e < E_NUM; ++e) p[e] = 0.0;
  for (int d = lane; d < D_DIM; d += 64) {
    double xv = (double)xr[d];
    const float* g = gW + (size_t)d * E_NUM;
#pragma unroll
    for (int e = 0; e < E_NUM; ++e) p[e] += xv * (double)g[e];
  }
#pragma unroll
  for (int off = 32; off > 0; off >>= 1) {
#pragma unroll
    for (int e = 0; e < E_NUM; ++e) p[e] += __shfl_xor(p[e], off, 64);
  }
  if (lane == 0) {
    double rs = (double)route_scale[0];
    double s[E_NUM];
#pragma unroll
    for (int e = 0; e < E_NUM; ++e) s[e] = rs / (1.0 + exp(-p[e]));
    int i1 = 0;
#pragma unroll
    for (int e = 1; e < E_NUM; ++e) if (s[e] > s[i1]) i1 = e;
    int i2 = (i1 == 0) ? 1 : 0;
#pragma unroll
    for (int e = 0; e < E_NUM; ++e) if (e != i1 && s[e] > s[i2]) i2 = e;
    double inv = 1.0 / (s[i1] + s[i2]);
    float o[E_NUM];
#pragma unroll
    for (int e = 0; e < E_NUM; ++e) o[e] = 0.f;
    o[i1] = (float)(s[i1] * inv);
    o[i2] = (float)(s[i2] * inv);
#pragma unroll
    for (int e = 0; e < E_NUM; ++e) gateT[(size_t)e * TOKENS + tok] = o[e];
    sel[tok] = i1 * 8 + i2;
  }
  const float4* x4 = (const float4*)xr;
  bf16x4* xb4 = (bf16x4*)(Xb + (size_t)tok * D_DIM);
#pragma unroll
  for (int i = 0; i < 4; ++i) {
    float4 v = x4[i * 64 + lane];
    bf16x4 o = { (bf16_t)v.x, (bf16_t)v.y, (bf16_t)v.z, (bf16_t)v.w };
    xb4[i * 64 + lane] = o;
  }
}

// ------------------------------------------------- Bt1 (N1 x 1024)
__global__ __launch_bounds__(256) void repack1_kernel(
    const float* __restrict__ W1, const float* __restrict__ Ws1,
    bf16_t* __restrict__ Bt1) {
  __shared__ float tile[32][33];
  int k0 = blockIdx.x * 32, n0 = blockIdx.y * 32;
  int tx = threadIdx.x, ty = threadIdx.y;
#pragma unroll
  for (int i = 0; i < 4; ++i) {
    int kl = ty + i * 8;
    int n = n0 + tx, k = k0 + kl;
    float v;
    if (n0 < 4096) v = W1[(size_t)(n >> 9) * (D_DIM * H_DIM) + (size_t)k * H_DIM + (n & 511)];
    else           v = Ws1[(size_t)k * H_DIM + (n - 4096)];
    tile[kl][tx] = v;
  }
  __syncthreads();
#pragma unroll
  for (int i = 0; i < 4; ++i) {
    int nl = ty + i * 8;
    Bt1[(size_t)(n0 + nl) * D_DIM + k0 + tx] = (bf16_t)tile[tx][nl];
  }
}

// ------------------------------------------------- Bt2e[e][d][h]
__global__ __launch_bounds__(256) void repack2e_kernel(
    const float* __restrict__ W2, const float* __restrict__ Ws2,
    bf16_t* __restrict__ Bt2e) {
  __shared__ float tile[32][33];
  int d0 = blockIdx.x * 32, h0 = blockIdx.y * 32, e = blockIdx.z;
  int tx = threadIdx.x, ty = threadIdx.y;
#pragma unroll
  for (int i = 0; i < 4; ++i) {
    int hl = ty + i * 8;
    int h = h0 + hl, d = d0 + tx;
    float v = (e < E_NUM) ? W2[((size_t)e * H_DIM + h) * D_DIM + d]
                          : Ws2[(size_t)h * D_DIM + d];
    tile[hl][tx] = v;
  }
  __syncthreads();
#pragma unroll
  for (int i = 0; i < 4; ++i) {
    int dl = ty + i * 8;
    Bt2e[((size_t)e * D_DIM + (d0 + dl)) * H_DIM + h0 + tx] = (bf16_t)tile[tx][dl];
  }
}

// ---------------------------------------------------------------- list build: 8 blocks (1/expert) x 256,
// coalesced gateT reads + next-chunk prefetch so the load latency hides under the scan.
__global__ __launch_bounds__(256) void listbuild_kernel(
    const float* __restrict__ gateT, const int* __restrict__ sel,
    int* __restrict__ perm, float* __restrict__ grow,
    int* __restrict__ tok2row, int* __restrict__ padcnt) {
  const int e = blockIdx.x;
  const int tid = threadIdx.x, lane = tid & 63, wid = tid >> 6;
  __shared__ int wsum[4];
  const float* row = gateT + (size_t)e * TOKENS;
  const int base = e * CAP;
  int running = 0;
  float gv = row[tid];                       // prefetch chunk 0
  for (int c = 0; c < TOKENS / 256; ++c) {
    float gv_next = (c + 1 < TOKENS / 256) ? row[(c + 1) * 256 + tid] : 0.f;
    const int tok = c * 256 + tid;
    const bool f = gv > 0.f;
    unsigned long long m = __ballot(f);
    int lanepre = __popcll(m & ((1ull << lane) - 1ull));
    if (lane == 0) wsum[wid] = __popcll(m);
    __syncthreads();
    int wbase = 0;
#pragma unroll
    for (int w2 = 0; w2 < 4; ++w2) if (w2 < wid) wbase += wsum[w2];
    const int tot = wsum[0] + wsum[1] + wsum[2] + wsum[3];
    if (f) {
      const int idx = running + wbase + lanepre;
      if (idx < CAP) {
        perm[base + idx] = tok;
        grow[base + idx] = gv;
        const int s = sel[tok];
        const int other = ((s >> 3) == e) ? (s & 7) : (s >> 3);
        tok2row[tok * 2 + (e > other ? 1 : 0)] = base + idx;
      }
    }
    running += tot;
    __syncthreads();
    gv = gv_next;
  }
  if (running > CAP) running = CAP;
  const int pc = (running + 127) & ~127;
  for (int i = running + tid; i < pc; i += 256) { perm[base + i] = 0; grow[base + i] = 0.f; }
  if (tid == 0) padcnt[e] = pc;
}

// ---------------------------------------------------------------- 3-buffer single-barrier GEMM core
__device__ __forceinline__ void gemm_core(
    const char* ga0, const char* ga1, const char* gb0, const char* gb1,
    int kiters, bf16_t* sA, bf16_t* sB, int wave, int lane, int wr, int wc,
    f32x4 (&acc)[4][4]) {
  const int kb = (lane >> 4) * 16;
  const int ar = wr * 64 + (lane & 15);
  const int br = wc * 64 + (lane & 15);
  auto stage = [&](int buf, int kk) {
    const size_t ko = (size_t)kk * 64;
    char* la = (char*)sA + buf * 8192 + wave * 1024;
    char* lb = (char*)sB + buf * 8192 + wave * 1024;
    __builtin_amdgcn_global_load_lds(
        (const __attribute__((address_space(1))) void*)(ga0 + ko),
        (__attribute__((address_space(3))) void*)la, 16, 0, 0);
    __builtin_amdgcn_global_load_lds(
        (const __attribute__((address_space(1))) void*)(ga1 + ko),
        (__attribute__((address_space(3))) void*)(la + 4096), 16, 0, 0);
    __builtin_amdgcn_global_load_lds(
        (const __attribute__((address_space(1))) void*)(gb0 + ko),
        (__attribute__((address_space(3))) void*)lb, 16, 0, 0);
    __builtin_amdgcn_global_load_lds(
        (const __attribute__((address_space(1))) void*)(gb1 + ko),
        (__attribute__((address_space(3))) void*)(lb + 4096), 16, 0, 0);
  };
  stage(0, 0);
  int nb = 1;
  for (int kk = 0; kk < kiters; ++kk) {
    if (kk + 1 < kiters) {
      stage(nb, kk + 1);
      asm volatile("s_waitcnt vmcnt(4)" ::: "memory");
    } else {
      asm volatile("s_waitcnt vmcnt(0)" ::: "memory");
    }
    __builtin_amdgcn_s_barrier();
    asm volatile("" ::: "memory");
    const int cur = (nb == 0) ? 2 : nb - 1;
    const char* bA = (const char*)sA + cur * 8192;
    const char* bB = (const char*)sB + cur * 8192;
    bf16x8 af[4], bfv[4];
#pragma unroll
    for (int m = 0; m < 4; ++m)
      af[m] = *(const bf16x8*)(bA + (size_t)(ar + m * 16) * 64 + kb);
#pragma unroll
    for (int n = 0; n < 4; ++n)
      bfv[n] = *(const bf16x8*)(bB + (size_t)(br + n * 16) * 64 + kb);
#pragma unroll
    for (int m = 0; m < 4; ++m)
#pragma unroll
      for (int n = 0; n < 4; ++n)
        acc[m][n] = __builtin_amdgcn_mfma_f32_16x16x32_bf16(af[m], bfv[n], acc[m][n], 0, 0, 0);
    asm volatile("" ::: "memory");
    nb = (nb == 2) ? 0 : nb + 1;
  }
}

// ---------------------------------------------------------------- GEMM1: Hs = gate * gelu(X[perm] @ W1[e]^T + b1)
__global__ __launch_bounds__(256) void gemm1e_kernel(
    const bf16_t* __restrict__ Xb, const bf16_t* __restrict__ Bt1,
    const int* __restrict__ perm, const float* __restrict__ grow,
    const int* __restrict__ padcnt,
    const float* __restrict__ b1, const float* __restrict__ bs1,
    bf16_t* __restrict__ Hs) {
  __shared__ bf16_t sA[3 * 128 * 32];
  __shared__ bf16_t sB[3 * 128 * 32];
  const int y = blockIdx.y;
  const int t = threadIdx.x, wave = t >> 6, lane = t & 63, wr = wave >> 1, wc = wave & 1;
  const int n0 = blockIdx.x * 128;   // N = 512
  const int r = t >> 2, cb = (t & 3) * 16;
  int e, rowbase, tok0, tok1;
  if (y < E_NUM * ETILES) {
    e = y / ETILES;
    const int lt = y - e * ETILES;
    if (lt * 128 >= padcnt[e]) return;
    rowbase = e * CAP + lt * 128;
    tok0 = perm[rowbase + r];
    tok1 = perm[rowbase + 64 + r];
  } else {
    e = E_NUM;
    const int st = y - E_NUM * ETILES;
    rowbase = SH_BASE + st * 128;
    tok0 = st * 128 + r;
    tok1 = st * 128 + 64 + r;
  }
  const char* ga0 = (const char*)Xb + (size_t)tok0 * 2048 + cb;
  const char* ga1 = (const char*)Xb + (size_t)tok1 * 2048 + cb;
  const bf16_t* W = Bt1 + (size_t)e * H_DIM * D_DIM;
  const char* gb0 = (const char*)W + (size_t)(n0 + r) * 2048 + cb;
  const char* gb1 = (const char*)W + (size_t)(n0 + 64 + r) * 2048 + cb;
  f32x4 acc[4][4];
#pragma unroll
  for (int i = 0; i < 4; ++i)
#pragma unroll
    for (int j = 0; j < 4; ++j) acc[i][j] = (f32x4){0.f, 0.f, 0.f, 0.f};
  gemm_core(ga0, ga1, gb0, gb1, D_DIM / 32, sA, sB, wave, lane, wr, wc, acc);

  const float* bias = (e < E_NUM) ? (b1 + e * H_DIM) : bs1;
#pragma unroll
  for (int m = 0; m < 4; ++m) {
    const int rloc = wr * 64 + m * 16 + (lane >> 4) * 4;
    float gr[4];
#pragma unroll
    for (int q = 0; q < 4; ++q)
      gr[q] = (e < E_NUM) ? grow[rowbase + rloc + q] : 1.0f;
#pragma unroll
    for (int n = 0; n < 4; ++n) {
      const int col = n0 + wc * 64 + n * 16 + (lane & 15);
      const float bv = bias[col];
#pragma unroll
      for (int q = 0; q < 4; ++q) {
        float v = gelu_fast(acc[m][n][q] + bv);
        Hs[(size_t)(rowbase + rloc + q) * H_DIM + col] = (bf16_t)(v * gr[q]);
      }
    }
  }
}

// ---------------------------------------------------------------- GEMM2 expert tiles: Ys(bf16) = acc + grow*b2[e]
__global__ __launch_bounds__(256) void gemm2e_kernel(
    const bf16_t* __restrict__ Hs, const bf16_t* __restrict__ Bt2e,
    const float* __restrict__ grow, const int* __restrict__ padcnt,
    const float* __restrict__ b2, bf16_t* __restrict__ Ys) {
  __shared__ bf16_t sA[3 * 128 * 32];
  __shared__ bf16_t sB[3 * 128 * 32];
  const int y = blockIdx.y;
  const int e = y / ETILES;
  const int lt = y - e * ETILES;
  if (lt * 128 >= padcnt[e]) return;
  const int rowbase = e * CAP + lt * 128;
  const int t = threadIdx.x, wave = t >> 6, lane = t & 63, wr = wave >> 1, wc = wave & 1;
  const int n0 = blockIdx.x * 128;   // N = 1024
  const int r = t >> 2, cb = (t & 3) * 16;
  const char* ga0 = (const char*)Hs + (size_t)(rowbase + r) * 1024 + cb;
  const char* ga1 = (const char*)Hs + (size_t)(rowbase + 64 + r) * 1024 + cb;
  const bf16_t* W = Bt2e + (size_t)e * D_DIM * H_DIM;
  const char* gb0 = (const char*)W + (size_t)(n0 + r) * 1024 + cb;
  const char* gb1 = (const char*)W + (size_t)(n0 + 64 + r) * 1024 + cb;
  f32x4 acc[4][4];
#pragma unroll
  for (int i = 0; i < 4; ++i)
#pragma unroll
    for (int j = 0; j < 4; ++j) acc[i][j] = (f32x4){0.f, 0.f, 0.f, 0.f};
  gemm_core(ga0, ga1, gb0, gb1, H_DIM / 32, sA, sB, wave, lane, wr, wc, acc);

  const float* bb = b2 + (size_t)e * D_DIM;
#pragma unroll
  for (int m = 0; m < 4; ++m) {
    const int rloc = wr * 64 + m * 16 + (lane >> 4) * 4;
    float gr[4];
#pragma unroll
    for (int q = 0; q < 4; ++q) gr[q] = grow[rowbase + rloc + q];
#pragma unroll
    for (int n = 0; n < 4; ++n) {
      const int col = n0 + wc * 64 + n * 16 + (lane & 15);
      const float bv = bb[col];
#pragma unroll
      for (int q = 0; q < 4; ++q)
        Ys[(size_t)(rowbase + rloc + q) * D_DIM + col] = (bf16_t)(acc[m][n][q] + gr[q] * bv);
    }
  }
}

// ---------------------------------------------------------------- GEMM2 shared tiles + combine
__global__ __launch_bounds__(256) void gemm2s_kernel(
    const bf16_t* __restrict__ Hs, const bf16_t* __restrict__ Bt2e,
    const int* __restrict__ tok2row, const float* __restrict__ bs2,
    const bf16_t* __restrict__ Ys, float* __restrict__ out) {
  __shared__ bf16_t sA[3 * 128 * 32];
  __shared__ bf16_t sB[3 * 128 * 32];
  const int tokbase = blockIdx.y * 128;
  const int rowbase = SH_BASE + tokbase;
  const int t = threadIdx.x, wave = t >> 6, lane = t & 63, wr = wave >> 1, wc = wave & 1;
  const int n0 = blockIdx.x * 128;   // N = 1024
  const int r = t >> 2, cb = (t & 3) * 16;
  const char* ga0 = (const char*)Hs + (size_t)(rowbase + r) * 1024 + cb;
  const char* ga1 = (const char*)Hs + (size_t)(rowbase + 64 + r) * 1024 + cb;
  const bf16_t* W = Bt2e + (size_t)E_NUM * D_DIM * H_DIM;
  const char* gb0 = (const char*)W + (size_t)(n0 + r) * 1024 + cb;
  const char* gb1 = (const char*)W + (size_t)(n0 + 64 + r) * 1024 + cb;
  f32x4 acc[4][4];
#pragma unroll
  for (int i = 0; i < 4; ++i)
#pragma unroll
    for (int j = 0; j < 4; ++j) acc[i][j] = (f32x4){0.f, 0.f, 0.f, 0.f};
  gemm_core(ga0, ga1, gb0, gb1, H_DIM / 32, sA, sB, wave, lane, wr, wc, acc);

#pragma unroll
  for (int m = 0; m < 4; ++m) {
    const int rloc = wr * 64 + m * 16 + (lane >> 4) * 4;
    int r0[4], r1[4];
#pragma unroll
    for (int q = 0; q < 4; ++q) {
      const int tok = tokbase + rloc + q;
      r0[q] = tok2row[tok * 2];
      r1[q] = tok2row[tok * 2 + 1];
    }
#pragma unroll
    for (int n = 0; n < 4; ++n) {
      const int col = n0 + wc * 64 + n * 16 + (lane & 15);
      const float bv = bs2[col];
#pragma unroll
      for (int q = 0; q < 4; ++q) {
        const int tok = tokbase + rloc + q;
        float y0 = (float)Ys[(size_t)r0[q] * D_DIM + col];
        float y1 = (float)Ys[(size_t)r1[q] * D_DIM + col];
        out[(size_t)tok * D_DIM + col] = acc[m][n][q] + bv + y0 + y1;
      }
    }
  }
}

// ---------------------------------------------------------------- launch
extern "C" void kernel_launch(void* const* d_in, const int* in_sizes, int n_in,
                              void* d_out, int out_size, void* d_ws, size_t ws_size,
                              hipStream_t stream) {
  (void)in_sizes; (void)n_in; (void)out_size; (void)ws_size;
  const float* x    = (const float*)d_in[0];
  const float* gW   = (const float*)d_in[1];
  const float* W1   = (const float*)d_in[2];
  const float* b1   = (const float*)d_in[3];
  const float* W2   = (const float*)d_in[4];
  const float* b2   = (const float*)d_in[5];
  const float* Ws1  = (const float*)d_in[6];
  const float* bs1  = (const float*)d_in[7];
  const float* Ws2  = (const float*)d_in[8];
  const float* bs2  = (const float*)d_in[9];
  const float* rsc  = (const float*)d_in[10];
  float* out = (float*)d_out;

  char* w = (char*)d_ws;
  float*  gateT = (float*)w;  w += (size_t)E_NUM * TOKENS * 4;       // 0.25 MB
  int*    sel   = (int*)w;    w += (size_t)TOKENS * 4;               // 32 KB
  bf16_t* Xb    = (bf16_t*)w; w += (size_t)TOKENS * D_DIM * 2;       // 16.8 MB
  bf16_t* Bt1   = (bf16_t*)w; w += (size_t)N1 * D_DIM * 2;           // 9.4 MB
  bf16_t* Bt2e  = (bf16_t*)w; w += (size_t)9 * D_DIM * H_DIM * 2;    // 9.4 MB
  bf16_t* Hs    = (bf16_t*)w; w += (size_t)HS_ROWS * H_DIM * 2;      // 33.6 MB
  bf16_t* Ys    = (bf16_t*)w; w += (size_t)EXP_ROWS * D_DIM * 2;     // 50.3 MB
  int*    perm  = (int*)w;    w += (size_t)EXP_ROWS * 4;             // 98 KB
  float*  grow  = (float*)w;  w += (size_t)EXP_ROWS * 4;             // 98 KB
  int*    tok2row = (int*)w;  w += (size_t)TOKENS * 2 * 4;           // 64 KB
  int*    padcnt  = (int*)w;                                         // 32 B

  routing_kernel<<<TOKENS / 4, 256, 0, stream>>>(x, gW, rsc, gateT, sel, Xb);
  listbuild_kernel<<<E_NUM, 256, 0, stream>>>(gateT, sel, perm, grow, tok2row, padcnt);
  repack1_kernel<<<dim3(D_DIM / 32, N1 / 32), dim3(32, 8), 0, stream>>>(W1, Ws1, Bt1);
  repack2e_kernel<<<dim3(D_DIM / 32, H_DIM / 32, 9), dim3(32, 8), 0, stream>>>(W2, Ws2, Bt2e);

  gemm1e_kernel<<<dim3(H_DIM / 128, E_NUM * ETILES + TOKENS / 128), 256, 0, stream>>>(
      Xb, Bt1, perm, grow, padcnt, b1, bs1, Hs);
  gemm2e_kernel<<<dim3(D_DIM / 128, E_NUM * ETILES), 256, 0, stream>>>(
      Hs, Bt2e, grow, padcnt, b2, Ys);
  gemm2s_kernel<<<dim3(D_DIM / 128, TOKENS / 128), 256, 0, stream>>>(
      Hs, Bt2e, tok2row, bs2, Ys, out);
}

// Round 6
// 175.928 us; speedup vs baseline: 1.3357x; 1.0424x over previous
//
#include <hip/hip_runtime.h>
#include <hip/hip_bf16.h>

// B=4, S=2048, D=1024, E=8, H=512, top-2 + shared expert
#define TOKENS 8192
#define D_DIM  1024
#define E_NUM  8
#define H_DIM  512
#define N1     4608            // E*H + H (Bt1 rows)
#define CAP    3072            // per-expert row capacity (~2048 expected, +26 sigma)
#define ETILES (CAP / 128)     // 24 tiles per expert segment
#define EXP_ROWS (E_NUM * CAP) // 24576 expert rows
#define SH_BASE  EXP_ROWS      // shared segment base in Hs row space
#define HS_ROWS (EXP_ROWS + TOKENS)  // 32768

typedef __bf16 bf16_t;
typedef __bf16 bf16x8 __attribute__((ext_vector_type(8)));
typedef __bf16 bf16x4 __attribute__((ext_vector_type(4)));
typedef float  f32x4  __attribute__((ext_vector_type(4)));

// tanh-form GELU, 7 VALU ops
__device__ __forceinline__ float gelu_fast(float v) {
  float w = v * v;
  float t = __builtin_fmaf(w, 0.10294307f, 2.30258835f);
  float z = v * t;
  float e = __builtin_amdgcn_exp2f(z);
  float r = __builtin_amdgcn_rcpf(e + 1.0f);
  return v - v * r;
}

// ---------------------------------------------------------------- routing (+ fused x->bf16 cast)
__global__ __launch_bounds__(256) void routing_kernel(
    const float* __restrict__ x, const float* __restrict__ gW,
    const float* __restrict__ route_scale, float* __restrict__ gateT,
    int* __restrict__ sel, bf16_t* __restrict__ Xb) {
  int tok  = blockIdx.x * 4 + (threadIdx.x >> 6);
  int lane = threadIdx.x & 63;
  const float* xr = x + (size_t)tok * D_DIM;
  double p[E_NUM];
#pragma unroll
  for (int e = 0; e < E_NUM; ++e) p[e] = 0.0;
  for (int d = lane; d < D_DIM; d += 64) {
    double xv = (double)xr[d];
    const float* g = gW + (size_t)d * E_NUM;
#pragma unroll
    for (int e = 0; e < E_NUM; ++e) p[e] += xv * (double)g[e];
  }
#pragma unroll
  for (int off = 32; off > 0; off >>= 1) {
#pragma unroll
    for (int e = 0; e < E_NUM; ++e) p[e] += __shfl_xor(p[e], off, 64);
  }
  if (lane == 0) {
    double rs = (double)route_scale[0];
    double s[E_NUM];
#pragma unroll
    for (int e = 0; e < E_NUM; ++e) s[e] = rs / (1.0 + exp(-p[e]));
    int i1 = 0;
#pragma unroll
    for (int e = 1; e < E_NUM; ++e) if (s[e] > s[i1]) i1 = e;
    int i2 = (i1 == 0) ? 1 : 0;
#pragma unroll
    for (int e = 0; e < E_NUM; ++e) if (e != i1 && s[e] > s[i2]) i2 = e;
    double inv = 1.0 / (s[i1] + s[i2]);
    float o[E_NUM];
#pragma unroll
    for (int e = 0; e < E_NUM; ++e) o[e] = 0.f;
    o[i1] = (float)(s[i1] * inv);
    o[i2] = (float)(s[i2] * inv);
#pragma unroll
    for (int e = 0; e < E_NUM; ++e) gateT[(size_t)e * TOKENS + tok] = o[e];
    sel[tok] = i1 * 8 + i2;
  }
  const float4* x4 = (const float4*)xr;
  bf16x4* xb4 = (bf16x4*)(Xb + (size_t)tok * D_DIM);
#pragma unroll
  for (int i = 0; i < 4; ++i) {
    float4 v = x4[i * 64 + lane];
    bf16x4 o = { (bf16_t)v.x, (bf16_t)v.y, (bf16_t)v.z, (bf16_t)v.w };
    xb4[i * 64 + lane] = o;
  }
}

// ------------------------------------------------- Bt1 (N1 x 1024)
__global__ __launch_bounds__(256) void repack1_kernel(
    const float* __restrict__ W1, const float* __restrict__ Ws1,
    bf16_t* __restrict__ Bt1) {
  __shared__ float tile[32][33];
  int k0 = blockIdx.x * 32, n0 = blockIdx.y * 32;
  int tx = threadIdx.x, ty = threadIdx.y;
#pragma unroll
  for (int i = 0; i < 4; ++i) {
    int kl = ty + i * 8;
    int n = n0 + tx, k = k0 + kl;
    float v;
    if (n0 < 4096) v = W1[(size_t)(n >> 9) * (D_DIM * H_DIM) + (size_t)k * H_DIM + (n & 511)];
    else           v = Ws1[(size_t)k * H_DIM + (n - 4096)];
    tile[kl][tx] = v;
  }
  __syncthreads();
#pragma unroll
  for (int i = 0; i < 4; ++i) {
    int nl = ty + i * 8;
    Bt1[(size_t)(n0 + nl) * D_DIM + k0 + tx] = (bf16_t)tile[tx][nl];
  }
}

// ------------------------------------------------- Bt2e[e][d][h]
__global__ __launch_bounds__(256) void repack2e_kernel(
    const float* __restrict__ W2, const float* __restrict__ Ws2,
    bf16_t* __restrict__ Bt2e) {
  __shared__ float tile[32][33];
  int d0 = blockIdx.x * 32, h0 = blockIdx.y * 32, e = blockIdx.z;
  int tx = threadIdx.x, ty = threadIdx.y;
#pragma unroll
  for (int i = 0; i < 4; ++i) {
    int hl = ty + i * 8;
    int h = h0 + hl, d = d0 + tx;
    float v = (e < E_NUM) ? W2[((size_t)e * H_DIM + h) * D_DIM + d]
                          : Ws2[(size_t)h * D_DIM + d];
    tile[hl][tx] = v;
  }
  __syncthreads();
#pragma unroll
  for (int i = 0; i < 4; ++i) {
    int dl = ty + i * 8;
    Bt2e[((size_t)e * D_DIM + (d0 + dl)) * H_DIM + h0 + tx] = (bf16_t)tile[tx][dl];
  }
}

// ---------------------------------------------------------------- list build: 8 blocks (1/expert) x 256
__global__ __launch_bounds__(256) void listbuild_kernel(
    const float* __restrict__ gateT, const int* __restrict__ sel,
    int* __restrict__ perm, float* __restrict__ grow,
    int* __restrict__ tok2row, int* __restrict__ padcnt) {
  const int e = blockIdx.x;
  const int tid = threadIdx.x, lane = tid & 63, wid = tid >> 6;
  __shared__ int wsum[4];
  const float* row = gateT + (size_t)e * TOKENS;
  const int base = e * CAP;
  int running = 0;
  float gv = row[tid];                       // prefetch chunk 0
  for (int c = 0; c < TOKENS / 256; ++c) {
    float gv_next = (c + 1 < TOKENS / 256) ? row[(c + 1) * 256 + tid] : 0.f;
    const int tok = c * 256 + tid;
    const bool f = gv > 0.f;
    unsigned long long m = __ballot(f);
    int lanepre = __popcll(m & ((1ull << lane) - 1ull));
    if (lane == 0) wsum[wid] = __popcll(m);
    __syncthreads();
    int wbase = 0;
#pragma unroll
    for (int w2 = 0; w2 < 4; ++w2) if (w2 < wid) wbase += wsum[w2];
    const int tot = wsum[0] + wsum[1] + wsum[2] + wsum[3];
    if (f) {
      const int idx = running + wbase + lanepre;
      if (idx < CAP) {
        perm[base + idx] = tok;
        grow[base + idx] = gv;
        const int s = sel[tok];
        const int other = ((s >> 3) == e) ? (s & 7) : (s >> 3);
        tok2row[tok * 2 + (e > other ? 1 : 0)] = base + idx;
      }
    }
    running += tot;
    __syncthreads();
    gv = gv_next;
  }
  if (running > CAP) running = CAP;
  const int pc = (running + 127) & ~127;
  for (int i = running + tid; i < pc; i += 256) { perm[base + i] = 0; grow[base + i] = 0.f; }
  if (tid == 0) padcnt[e] = pc;
}

// ---------------------------------------------------------------- 4-buffer depth-2-prefetch GEMM core
// 128x128 tile, BK=32, 4 waves 2x2, 16x16x32 MFMA. One s_barrier per K-step;
// tiles k+1,k+2 in flight (counted vmcnt(8), never drained mid-loop).
// Buffer reuse distance 4 with wave skew <=1 (single barrier) => race-free:
// readers of buf (k+2)&3 finished tile k-2 before barrier k-1, which the
// staging wave has already passed. LDS slot-XOR swizzle (slot ^= (row>>1)&3)
// applied on BOTH sides: pre-swizzled per-lane global source (LDS dest linear,
// per gload_lds rules) + swizzled read offsets (loop-invariant).
__device__ __forceinline__ void gemm_core(
    const char* ga0, const char* ga1, const char* gb0, const char* gb1,
    int kiters, bf16_t* sA, bf16_t* sB, int wave, int lane, int wr, int wc,
    f32x4 (&acc)[4][4]) {
  const int kb = (lane >> 4) * 16;
  const int ar = wr * 64 + (lane & 15);
  const int br = wc * 64 + (lane & 15);
  int aoff[4], boff[4];
#pragma unroll
  for (int m = 0; m < 4; ++m) {
    const int rowa = ar + m * 16;
    aoff[m] = rowa * 64 + (kb ^ ((((rowa >> 1) & 3)) << 4));
    const int rowb = br + m * 16;
    boff[m] = rowb * 64 + (kb ^ ((((rowb >> 1) & 3)) << 4));
  }
  auto stage = [&](int buf, int kk) {
    const size_t ko = (size_t)kk * 64;
    char* la = (char*)sA + buf * 8192 + wave * 1024;
    char* lb = (char*)sB + buf * 8192 + wave * 1024;
    __builtin_amdgcn_global_load_lds(
        (const __attribute__((address_space(1))) void*)(ga0 + ko),
        (__attribute__((address_space(3))) void*)la, 16, 0, 0);
    __builtin_amdgcn_global_load_lds(
        (const __attribute__((address_space(1))) void*)(ga1 + ko),
        (__attribute__((address_space(3))) void*)(la + 4096), 16, 0, 0);
    __builtin_amdgcn_global_load_lds(
        (const __attribute__((address_space(1))) void*)(gb0 + ko),
        (__attribute__((address_space(3))) void*)lb, 16, 0, 0);
    __builtin_amdgcn_global_load_lds(
        (const __attribute__((address_space(1))) void*)(gb1 + ko),
        (__attribute__((address_space(3))) void*)(lb + 4096), 16, 0, 0);
  };
  stage(0, 0);
  stage(1, 1);                     // kiters >= 2 always
  for (int kk = 0; kk < kiters; ++kk) {
    if (kk + 2 < kiters) {
      stage((kk + 2) & 3, kk + 2);
      asm volatile("s_waitcnt vmcnt(8)" ::: "memory");   // tile kk landed
    } else if (kk + 1 < kiters) {
      asm volatile("s_waitcnt vmcnt(4)" ::: "memory");
    } else {
      asm volatile("s_waitcnt vmcnt(0)" ::: "memory");
    }
    __builtin_amdgcn_s_barrier();
    asm volatile("" ::: "memory");
    const char* bA = (const char*)sA + (kk & 3) * 8192;
    const char* bB = (const char*)sB + (kk & 3) * 8192;
    bf16x8 af[4], bfv[4];
#pragma unroll
    for (int m = 0; m < 4; ++m)
      af[m] = *(const bf16x8*)(bA + aoff[m]);
#pragma unroll
    for (int n = 0; n < 4; ++n)
      bfv[n] = *(const bf16x8*)(bB + boff[n]);
#pragma unroll
    for (int m = 0; m < 4; ++m)
#pragma unroll
      for (int n = 0; n < 4; ++n)
        acc[m][n] = __builtin_amdgcn_mfma_f32_16x16x32_bf16(af[m], bfv[n], acc[m][n], 0, 0, 0);
    asm volatile("" ::: "memory");
  }
}

// staging source column with slot-XOR pre-swizzle (inverse of read swizzle)
__device__ __forceinline__ int swz_cb(int t) {
  return ((t & 3) ^ ((t >> 3) & 3)) * 16;
}

// ---------------------------------------------------------------- GEMM1: Hs = gate * gelu(X[perm] @ W1[e]^T + b1)
__global__ __launch_bounds__(256) void gemm1e_kernel(
    const bf16_t* __restrict__ Xb, const bf16_t* __restrict__ Bt1,
    const int* __restrict__ perm, const float* __restrict__ grow,
    const int* __restrict__ padcnt,
    const float* __restrict__ b1, const float* __restrict__ bs1,
    bf16_t* __restrict__ Hs) {
  __shared__ bf16_t sA[4 * 128 * 32];
  __shared__ bf16_t sB[4 * 128 * 32];
  const int y = blockIdx.y;
  const int t = threadIdx.x, wave = t >> 6, lane = t & 63, wr = wave >> 1, wc = wave & 1;
  const int n0 = blockIdx.x * 128;   // N = 512
  const int r = t >> 2, cb = swz_cb(t);
  int e, rowbase, tok0, tok1;
  if (y < E_NUM * ETILES) {
    e = y / ETILES;
    const int lt = y - e * ETILES;
    if (lt * 128 >= padcnt[e]) return;
    rowbase = e * CAP + lt * 128;
    tok0 = perm[rowbase + r];
    tok1 = perm[rowbase + 64 + r];
  } else {
    e = E_NUM;
    const int st = y - E_NUM * ETILES;
    rowbase = SH_BASE + st * 128;
    tok0 = st * 128 + r;
    tok1 = st * 128 + 64 + r;
  }
  const char* ga0 = (const char*)Xb + (size_t)tok0 * 2048 + cb;
  const char* ga1 = (const char*)Xb + (size_t)tok1 * 2048 + cb;
  const bf16_t* W = Bt1 + (size_t)e * H_DIM * D_DIM;
  const char* gb0 = (const char*)W + (size_t)(n0 + r) * 2048 + cb;
  const char* gb1 = (const char*)W + (size_t)(n0 + 64 + r) * 2048 + cb;
  f32x4 acc[4][4];
#pragma unroll
  for (int i = 0; i < 4; ++i)
#pragma unroll
    for (int j = 0; j < 4; ++j) acc[i][j] = (f32x4){0.f, 0.f, 0.f, 0.f};
  gemm_core(ga0, ga1, gb0, gb1, D_DIM / 32, sA, sB, wave, lane, wr, wc, acc);

  const float* bias = (e < E_NUM) ? (b1 + e * H_DIM) : bs1;
#pragma unroll
  for (int m = 0; m < 4; ++m) {
    const int rloc = wr * 64 + m * 16 + (lane >> 4) * 4;
    float gr[4];
#pragma unroll
    for (int q = 0; q < 4; ++q)
      gr[q] = (e < E_NUM) ? grow[rowbase + rloc + q] : 1.0f;
#pragma unroll
    for (int n = 0; n < 4; ++n) {
      const int col = n0 + wc * 64 + n * 16 + (lane & 15);
      const float bv = bias[col];
#pragma unroll
      for (int q = 0; q < 4; ++q) {
        float v = gelu_fast(acc[m][n][q] + bv);
        Hs[(size_t)(rowbase + rloc + q) * H_DIM + col] = (bf16_t)(v * gr[q]);
      }
    }
  }
}

// ---------------------------------------------------------------- GEMM2 expert tiles: Ys(bf16) = acc + grow*b2[e]
__global__ __launch_bounds__(256) void gemm2e_kernel(
    const bf16_t* __restrict__ Hs, const bf16_t* __restrict__ Bt2e,
    const float* __restrict__ grow, const int* __restrict__ padcnt,
    const float* __restrict__ b2, bf16_t* __restrict__ Ys) {
  __shared__ bf16_t sA[4 * 128 * 32];
  __shared__ bf16_t sB[4 * 128 * 32];
  const int y = blockIdx.y;
  const int e = y / ETILES;
  const int lt = y - e * ETILES;
  if (lt * 128 >= padcnt[e]) return;
  const int rowbase = e * CAP + lt * 128;
  const int t = threadIdx.x, wave = t >> 6, lane = t & 63, wr = wave >> 1, wc = wave & 1;
  const int n0 = blockIdx.x * 128;   // N = 1024
  const int r = t >> 2, cb = swz_cb(t);
  const char* ga0 = (const char*)Hs + (size_t)(rowbase + r) * 1024 + cb;
  const char* ga1 = (const char*)Hs + (size_t)(rowbase + 64 + r) * 1024 + cb;
  const bf16_t* W = Bt2e + (size_t)e * D_DIM * H_DIM;
  const char* gb0 = (const char*)W + (size_t)(n0 + r) * 1024 + cb;
  const char* gb1 = (const char*)W + (size_t)(n0 + 64 + r) * 1024 + cb;
  f32x4 acc[4][4];
#pragma unroll
  for (int i = 0; i < 4; ++i)
#pragma unroll
    for (int j = 0; j < 4; ++j) acc[i][j] = (f32x4){0.f, 0.f, 0.f, 0.f};
  gemm_core(ga0, ga1, gb0, gb1, H_DIM / 32, sA, sB, wave, lane, wr, wc, acc);

  const float* bb = b2 + (size_t)e * D_DIM;
#pragma unroll
  for (int m = 0; m < 4; ++m) {
    const int rloc = wr * 64 + m * 16 + (lane >> 4) * 4;
    float gr[4];
#pragma unroll
    for (int q = 0; q < 4; ++q) gr[q] = grow[rowbase + rloc + q];
#pragma unroll
    for (int n = 0; n < 4; ++n) {
      const int col = n0 + wc * 64 + n * 16 + (lane & 15);
      const float bv = bb[col];
#pragma unroll
      for (int q = 0; q < 4; ++q)
        Ys[(size_t)(rowbase + rloc + q) * D_DIM + col] = (bf16_t)(acc[m][n][q] + gr[q] * bv);
    }
  }
}

// ---------------------------------------------------------------- GEMM2 shared tiles + combine
__global__ __launch_bounds__(256) void gemm2s_kernel(
    const bf16_t* __restrict__ Hs, const bf16_t* __restrict__ Bt2e,
    const int* __restrict__ tok2row, const float* __restrict__ bs2,
    const bf16_t* __restrict__ Ys, float* __restrict__ out) {
  __shared__ bf16_t sA[4 * 128 * 32];
  __shared__ bf16_t sB[4 * 128 * 32];
  const int tokbase = blockIdx.y * 128;
  const int rowbase = SH_BASE + tokbase;
  const int t = threadIdx.x, wave = t >> 6, lane = t & 63, wr = wave >> 1, wc = wave & 1;
  const int n0 = blockIdx.x * 128;   // N = 1024
  const int r = t >> 2, cb = swz_cb(t);
  const char* ga0 = (const char*)Hs + (size_t)(rowbase + r) * 1024 + cb;
  const char* ga1 = (const char*)Hs + (size_t)(rowbase + 64 + r) * 1024 + cb;
  const bf16_t* W = Bt2e + (size_t)E_NUM * D_DIM * H_DIM;
  const char* gb0 = (const char*)W + (size_t)(n0 + r) * 1024 + cb;
  const char* gb1 = (const char*)W + (size_t)(n0 + 64 + r) * 1024 + cb;
  f32x4 acc[4][4];
#pragma unroll
  for (int i = 0; i < 4; ++i)
#pragma unroll
    for (int j = 0; j < 4; ++j) acc[i][j] = (f32x4){0.f, 0.f, 0.f, 0.f};
  gemm_core(ga0, ga1, gb0, gb1, H_DIM / 32, sA, sB, wave, lane, wr, wc, acc);

#pragma unroll
  for (int m = 0; m < 4; ++m) {
    const int rloc = wr * 64 + m * 16 + (lane >> 4) * 4;
    int r0[4], r1[4];
#pragma unroll
    for (int q = 0; q < 4; ++q) {
      const int tok = tokbase + rloc + q;
      r0[q] = tok2row[tok * 2];
      r1[q] = tok2row[tok * 2 + 1];
    }
#pragma unroll
    for (int n = 0; n < 4; ++n) {
      const int col = n0 + wc * 64 + n * 16 + (lane & 15);
      const float bv = bs2[col];
#pragma unroll
      for (int q = 0; q < 4; ++q) {
        const int tok = tokbase + rloc + q;
        float y0 = (float)Ys[(size_t)r0[q] * D_DIM + col];
        float y1 = (float)Ys[(size_t)r1[q] * D_DIM + col];
        out[(size_t)tok * D_DIM + col] = acc[m][n][q] + bv + y0 + y1;
      }
    }
  }
}

// ---------------------------------------------------------------- launch
extern "C" void kernel_launch(void* const* d_in, const int* in_sizes, int n_in,
                              void* d_out, int out_size, void* d_ws, size_t ws_size,
                              hipStream_t stream) {
  (void)in_sizes; (void)n_in; (void)out_size; (void)ws_size;
  const float* x    = (const float*)d_in[0];
  const float* gW   = (const float*)d_in[1];
  const float* W1   = (const float*)d_in[2];
  const float* b1   = (const float*)d_in[3];
  const float* W2   = (const float*)d_in[4];
  const float* b2   = (const float*)d_in[5];
  const float* Ws1  = (const float*)d_in[6];
  const float* bs1  = (const float*)d_in[7];
  const float* Ws2  = (const float*)d_in[8];
  const float* bs2  = (const float*)d_in[9];
  const float* rsc  = (const float*)d_in[10];
  float* out = (float*)d_out;

  char* w = (char*)d_ws;
  float*  gateT = (float*)w;  w += (size_t)E_NUM * TOKENS * 4;       // 0.25 MB
  int*    sel   = (int*)w;    w += (size_t)TOKENS * 4;               // 32 KB
  bf16_t* Xb    = (bf16_t*)w; w += (size_t)TOKENS * D_DIM * 2;       // 16.8 MB
  bf16_t* Bt1   = (bf16_t*)w; w += (size_t)N1 * D_DIM * 2;           // 9.4 MB
  bf16_t* Bt2e  = (bf16_t*)w; w += (size_t)9 * D_DIM * H_DIM * 2;    // 9.4 MB
  bf16_t* Hs    = (bf16_t*)w; w += (size_t)HS_ROWS * H_DIM * 2;      // 33.6 MB
  bf16_t* Ys    = (bf16_t*)w; w += (size_t)EXP_ROWS * D_DIM * 2;     // 50.3 MB
  int*    perm  = (int*)w;    w += (size_t)EXP_ROWS * 4;             // 98 KB
  float*  grow  = (float*)w;  w += (size_t)EXP_ROWS * 4;             // 98 KB
  int*    tok2row = (int*)w;  w += (size_t)TOKENS * 2 * 4;           // 64 KB
  int*    padcnt  = (int*)w;                                         // 32 B

  routing_kernel<<<TOKENS / 4, 256, 0, stream>>>(x, gW, rsc, gateT, sel, Xb);
  listbuild_kernel<<<E_NUM, 256, 0, stream>>>(gateT, sel, perm, grow, tok2row, padcnt);
  repack1_kernel<<<dim3(D_DIM / 32, N1 / 32), dim3(32, 8), 0, stream>>>(W1, Ws1, Bt1);
  repack2e_kernel<<<dim3(D_DIM / 32, H_DIM / 32, 9), dim3(32, 8), 0, stream>>>(W2, Ws2, Bt2e);

  gemm1e_kernel<<<dim3(H_DIM / 128, E_NUM * ETILES + TOKENS / 128), 256, 0, stream>>>(
      Xb, Bt1, perm, grow, padcnt, b1, bs1, Hs);
  gemm2e_kernel<<<dim3(D_DIM / 128, E_NUM * ETILES), 256, 0, stream>>>(
      Hs, Bt2e, grow, padcnt, b2, Ys);
  gemm2s_kernel<<<dim3(D_DIM / 128, TOKENS / 128), 256, 0, stream>>>(
      Hs, Bt2e, tok2row, bs2, Ys, out);
}

// Round 7
// 157.989 us; speedup vs baseline: 1.4873x; 1.1135x over previous
//
#include <hip/hip_runtime.h>
#include <hip/hip_bf16.h>

// B=4, S=2048, D=1024, E=8, H=512, top-2 + shared expert
#define TOKENS 8192
#define D_DIM  1024
#define E_NUM  8
#define H_DIM  512
#define N1     4608            // E*H + H (Bt1 rows)
#define CAP    3072            // per-expert row capacity (~2048 expected, +26 sigma)
#define ET256  (CAP / 256)     // 12 tiles of 256 per expert segment
#define EXP_ROWS (E_NUM * CAP) // 24576 expert rows
#define SH_BASE  EXP_ROWS      // shared segment base in Hs row space
#define HS_ROWS (EXP_ROWS + TOKENS)  // 32768

typedef __bf16 bf16_t;
typedef __bf16 bf16x8 __attribute__((ext_vector_type(8)));
typedef __bf16 bf16x4 __attribute__((ext_vector_type(4)));
typedef float  f32x4  __attribute__((ext_vector_type(4)));

// tanh-form GELU, 7 VALU ops
__device__ __forceinline__ float gelu_fast(float v) {
  float w = v * v;
  float t = __builtin_fmaf(w, 0.10294307f, 2.30258835f);
  float z = v * t;
  float e = __builtin_amdgcn_exp2f(z);
  float r = __builtin_amdgcn_rcpf(e + 1.0f);
  return v - v * r;
}

// ---------------------------------------------------------------- routing (+ fused x->bf16 cast)
__global__ __launch_bounds__(256) void routing_kernel(
    const float* __restrict__ x, const float* __restrict__ gW,
    const float* __restrict__ route_scale, float* __restrict__ gateT,
    int* __restrict__ sel, bf16_t* __restrict__ Xb) {
  int tok  = blockIdx.x * 4 + (threadIdx.x >> 6);
  int lane = threadIdx.x & 63;
  const float* xr = x + (size_t)tok * D_DIM;
  double p[E_NUM];
#pragma unroll
  for (int e = 0; e < E_NUM; ++e) p[e] = 0.0;
  for (int d = lane; d < D_DIM; d += 64) {
    double xv = (double)xr[d];
    const float* g = gW + (size_t)d * E_NUM;
#pragma unroll
    for (int e = 0; e < E_NUM; ++e) p[e] += xv * (double)g[e];
  }
#pragma unroll
  for (int off = 32; off > 0; off >>= 1) {
#pragma unroll
    for (int e = 0; e < E_NUM; ++e) p[e] += __shfl_xor(p[e], off, 64);
  }
  if (lane == 0) {
    double rs = (double)route_scale[0];
    double s[E_NUM];
#pragma unroll
    for (int e = 0; e < E_NUM; ++e) s[e] = rs / (1.0 + exp(-p[e]));
    int i1 = 0;
#pragma unroll
    for (int e = 1; e < E_NUM; ++e) if (s[e] > s[i1]) i1 = e;
    int i2 = (i1 == 0) ? 1 : 0;
#pragma unroll
    for (int e = 0; e < E_NUM; ++e) if (e != i1 && s[e] > s[i2]) i2 = e;
    double inv = 1.0 / (s[i1] + s[i2]);
    float o[E_NUM];
#pragma unroll
    for (int e = 0; e < E_NUM; ++e) o[e] = 0.f;
    o[i1] = (float)(s[i1] * inv);
    o[i2] = (float)(s[i2] * inv);
#pragma unroll
    for (int e = 0; e < E_NUM; ++e) gateT[(size_t)e * TOKENS + tok] = o[e];
    sel[tok] = i1 * 8 + i2;
  }
  const float4* x4 = (const float4*)xr;
  bf16x4* xb4 = (bf16x4*)(Xb + (size_t)tok * D_DIM);
#pragma unroll
  for (int i = 0; i < 4; ++i) {
    float4 v = x4[i * 64 + lane];
    bf16x4 o = { (bf16_t)v.x, (bf16_t)v.y, (bf16_t)v.z, (bf16_t)v.w };
    xb4[i * 64 + lane] = o;
  }
}

// ------------------------------------------------- Bt1 (N1 x 1024)
__global__ __launch_bounds__(256) void repack1_kernel(
    const float* __restrict__ W1, const float* __restrict__ Ws1,
    bf16_t* __restrict__ Bt1) {
  __shared__ float tile[32][33];
  int k0 = blockIdx.x * 32, n0 = blockIdx.y * 32;
  int tx = threadIdx.x, ty = threadIdx.y;
#pragma unroll
  for (int i = 0; i < 4; ++i) {
    int kl = ty + i * 8;
    int n = n0 + tx, k = k0 + kl;
    float v;
    if (n0 < 4096) v = W1[(size_t)(n >> 9) * (D_DIM * H_DIM) + (size_t)k * H_DIM + (n & 511)];
    else           v = Ws1[(size_t)k * H_DIM + (n - 4096)];
    tile[kl][tx] = v;
  }
  __syncthreads();
#pragma unroll
  for (int i = 0; i < 4; ++i) {
    int nl = ty + i * 8;
    Bt1[(size_t)(n0 + nl) * D_DIM + k0 + tx] = (bf16_t)tile[tx][nl];
  }
}

// ------------------------------------------------- Bt2e[e][d][h]
__global__ __launch_bounds__(256) void repack2e_kernel(
    const float* __restrict__ W2, const float* __restrict__ Ws2,
    bf16_t* __restrict__ Bt2e) {
  __shared__ float tile[32][33];
  int d0 = blockIdx.x * 32, h0 = blockIdx.y * 32, e = blockIdx.z;
  int tx = threadIdx.x, ty = threadIdx.y;
#pragma unroll
  for (int i = 0; i < 4; ++i) {
    int hl = ty + i * 8;
    int h = h0 + hl, d = d0 + tx;
    float v = (e < E_NUM) ? W2[((size_t)e * H_DIM + h) * D_DIM + d]
                          : Ws2[(size_t)h * D_DIM + d];
    tile[hl][tx] = v;
  }
  __syncthreads();
#pragma unroll
  for (int i = 0; i < 4; ++i) {
    int dl = ty + i * 8;
    Bt2e[((size_t)e * D_DIM + (d0 + dl)) * H_DIM + h0 + tx] = (bf16_t)tile[tx][dl];
  }
}

// ---------------------------------------------------------------- list build: 8 blocks (1/expert) x 256, pads to x256
__global__ __launch_bounds__(256) void listbuild_kernel(
    const float* __restrict__ gateT, const int* __restrict__ sel,
    int* __restrict__ perm, float* __restrict__ grow,
    int* __restrict__ tok2row, int* __restrict__ padcnt) {
  const int e = blockIdx.x;
  const int tid = threadIdx.x, lane = tid & 63, wid = tid >> 6;
  __shared__ int wsum[4];
  const float* row = gateT + (size_t)e * TOKENS;
  const int base = e * CAP;
  int running = 0;
  float gv = row[tid];                       // prefetch chunk 0
  for (int c = 0; c < TOKENS / 256; ++c) {
    float gv_next = (c + 1 < TOKENS / 256) ? row[(c + 1) * 256 + tid] : 0.f;
    const int tok = c * 256 + tid;
    const bool f = gv > 0.f;
    unsigned long long m = __ballot(f);
    int lanepre = __popcll(m & ((1ull << lane) - 1ull));
    if (lane == 0) wsum[wid] = __popcll(m);
    __syncthreads();
    int wbase = 0;
#pragma unroll
    for (int w2 = 0; w2 < 4; ++w2) if (w2 < wid) wbase += wsum[w2];
    const int tot = wsum[0] + wsum[1] + wsum[2] + wsum[3];
    if (f) {
      const int idx = running + wbase + lanepre;
      if (idx < CAP) {
        perm[base + idx] = tok;
        grow[base + idx] = gv;
        const int s = sel[tok];
        const int other = ((s >> 3) == e) ? (s & 7) : (s >> 3);
        tok2row[tok * 2 + (e > other ? 1 : 0)] = base + idx;
      }
    }
    running += tot;
    __syncthreads();
    gv = gv_next;
  }
  if (running > CAP) running = CAP;
  const int pc = (running + 255) & ~255;     // pad to 256-row tiles
  for (int i = running + tid; i < pc; i += 256) { perm[base + i] = 0; grow[base + i] = 0.f; }
  if (tid == 0) padcnt[e] = pc;
}

// ---------------------------------------------------------------- 256x256 BK=64 8-wave GEMM core
// 8 waves (2M x 4N), per-wave output 128x64 (acc[8][4] of 16x16 frags), LDS 128KB
// double-buffer. Per K-tile: one counted wait + one barrier; stage tile t+1 AFTER
// the barrier (so the buffer being overwritten is provably free), its loads get a
// full iteration (~2000cy) to land before next iter's vmcnt.
// LDS layout per buffer (64KB): A[half][128][64]bf16 (32KB) then B same.
// 16B-slot swizzle: LDS[row][s] = global[row][s ^ (row&7)]; staging pre-swizzles the
// per-lane GLOBAL source column (dest stays linear per gload_lds rules); reads XOR
// the slot with (row&7) -> 2 lanes/bank-quad (free, m136).
__device__ __forceinline__ void gemm_core256(
    const char* ga0, const char* ga1, const char* ga2, const char* ga3,
    const char* gb0, const char* gb1, const char* gb2, const char* gb3,
    int ktiles, char* lds, int wid, int lane, f32x4 (&acc)[8][4]) {
  const int wm = wid >> 2, wn = wid & 3;
  const int lA = lane & 15, kq = lane >> 4;
  const int slot0 = (kq ^ (lA & 7)) * 16;
  const int slot1 = ((4 + kq) ^ (lA & 7)) * 16;

  auto stage = [&](int buf, int t) {
    char* dA = lds + buf * 65536 + wid * 1024;
    char* dB = dA + 32768;
    const size_t ko = (size_t)t * 128;
    __builtin_amdgcn_global_load_lds((const __attribute__((address_space(1))) void*)(ga0 + ko),
        (__attribute__((address_space(3))) void*)(dA + 0 * 8192), 16, 0, 0);
    __builtin_amdgcn_global_load_lds((const __attribute__((address_space(1))) void*)(ga1 + ko),
        (__attribute__((address_space(3))) void*)(dA + 1 * 8192), 16, 0, 0);
    __builtin_amdgcn_global_load_lds((const __attribute__((address_space(1))) void*)(ga2 + ko),
        (__attribute__((address_space(3))) void*)(dA + 2 * 8192), 16, 0, 0);
    __builtin_amdgcn_global_load_lds((const __attribute__((address_space(1))) void*)(ga3 + ko),
        (__attribute__((address_space(3))) void*)(dA + 3 * 8192), 16, 0, 0);
    __builtin_amdgcn_global_load_lds((const __attribute__((address_space(1))) void*)(gb0 + ko),
        (__attribute__((address_space(3))) void*)(dB + 0 * 8192), 16, 0, 0);
    __builtin_amdgcn_global_load_lds((const __attribute__((address_space(1))) void*)(gb1 + ko),
        (__attribute__((address_space(3))) void*)(dB + 1 * 8192), 16, 0, 0);
    __builtin_amdgcn_global_load_lds((const __attribute__((address_space(1))) void*)(gb2 + ko),
        (__attribute__((address_space(3))) void*)(dB + 2 * 8192), 16, 0, 0);
    __builtin_amdgcn_global_load_lds((const __attribute__((address_space(1))) void*)(gb3 + ko),
        (__attribute__((address_space(3))) void*)(dB + 3 * 8192), 16, 0, 0);
  };

  stage(0, 0);
  for (int t = 0; t < ktiles; ++t) {
    const int b = t & 1;
    asm volatile("s_waitcnt vmcnt(0)" ::: "memory");   // own tile-t loads landed (issued 1 iter ago)
    __builtin_amdgcn_s_barrier();                      // => ALL waves' tile-t landed; all done with buf b^1
    asm volatile("" ::: "memory");
    if (t + 1 < ktiles) stage(b ^ 1, t + 1);
    const char* Ab = lds + b * 65536 + wm * 16384;
    const char* Bb = lds + b * 65536 + 32768 + (wn >> 1) * 16384 + ((wn & 1) * 64) * 128;
    bf16x8 bfv[4][2];
#pragma unroll
    for (int nf = 0; nf < 4; ++nf) {
      const int rb = (nf * 16 + lA) * 128;
      bfv[nf][0] = *(const bf16x8*)(Bb + rb + slot0);
      bfv[nf][1] = *(const bf16x8*)(Bb + rb + slot1);
    }
#pragma unroll
    for (int qm = 0; qm < 2; ++qm) {
      bf16x8 af[4][2];
#pragma unroll
      for (int i = 0; i < 4; ++i) {
        const int ra = ((qm * 4 + i) * 16 + lA) * 128;
        af[i][0] = *(const bf16x8*)(Ab + ra + slot0);
        af[i][1] = *(const bf16x8*)(Ab + ra + slot1);
      }
      __builtin_amdgcn_s_setprio(1);
#pragma unroll
      for (int i = 0; i < 4; ++i)
#pragma unroll
        for (int nf = 0; nf < 4; ++nf) {
          acc[qm * 4 + i][nf] = __builtin_amdgcn_mfma_f32_16x16x32_bf16(af[i][0], bfv[nf][0], acc[qm * 4 + i][nf], 0, 0, 0);
          acc[qm * 4 + i][nf] = __builtin_amdgcn_mfma_f32_16x16x32_bf16(af[i][1], bfv[nf][1], acc[qm * 4 + i][nf], 0, 0, 0);
        }
      __builtin_amdgcn_s_setprio(0);
      __builtin_amdgcn_sched_barrier(0);
    }
  }
}

// staging source column byte with slot pre-swizzle (inverse of read swizzle)
__device__ __forceinline__ int swz_src(int lane) {
  return ((lane & 7) ^ ((lane >> 3) & 7)) * 16;
}

// ---------------------------------------------------------------- GEMM1: Hs = gate * gelu(X[perm] @ W1[e]^T + b1)
__global__ __launch_bounds__(512, 2) void gemm1e_kernel(
    const bf16_t* __restrict__ Xb, const bf16_t* __restrict__ Bt1,
    const int* __restrict__ perm, const float* __restrict__ grow,
    const int* __restrict__ padcnt,
    const float* __restrict__ b1, const float* __restrict__ bs1,
    bf16_t* __restrict__ Hs) {
  __shared__ bf16_t sL[65536];           // 128 KB
  const int t = threadIdx.x, wid = t >> 6, lane = t & 63;
  const int y = blockIdx.y;
  int e, rowbase;
  if (y < E_NUM * ET256) {
    e = y / ET256;
    const int lt = y - e * ET256;
    if (lt * 256 >= padcnt[e]) return;
    rowbase = e * CAP + lt * 256;
  } else {
    e = E_NUM;
    rowbase = SH_BASE + (y - E_NUM * ET256) * 256;
  }
  const int n0 = blockIdx.x * 256;       // N = 512
  const int rl = wid * 8 + (lane >> 3);
  const int sc = swz_src(lane);
  const char *ga[4], *gb[4];
#pragma unroll
  for (int g = 0; g < 4; ++g) {
    const int r = g * 64 + rl;
    const int tok = (e < E_NUM) ? perm[rowbase + r] : (rowbase - SH_BASE + r);
    ga[g] = (const char*)Xb + (size_t)tok * 2048 + sc;
    gb[g] = (const char*)(Bt1 + (size_t)e * H_DIM * D_DIM) + (size_t)(n0 + r) * 2048 + sc;
  }
  f32x4 acc[8][4];
#pragma unroll
  for (int i = 0; i < 8; ++i)
#pragma unroll
    for (int j = 0; j < 4; ++j) acc[i][j] = (f32x4){0.f, 0.f, 0.f, 0.f};
  gemm_core256(ga[0], ga[1], ga[2], ga[3], gb[0], gb[1], gb[2], gb[3],
               D_DIM / 64, (char*)sL, wid, lane, acc);

  const int wm = wid >> 2, wn = wid & 3, lA = lane & 15;
  const float* bias = (e < E_NUM) ? (b1 + e * H_DIM) : bs1;
#pragma unroll
  for (int mf = 0; mf < 8; ++mf) {
    const int rloc = wm * 128 + mf * 16 + (lane >> 4) * 4;
    float gr[4];
#pragma unroll
    for (int q = 0; q < 4; ++q)
      gr[q] = (e < E_NUM) ? grow[rowbase + rloc + q] : 1.0f;
#pragma unroll
    for (int nf = 0; nf < 4; ++nf) {
      const int col = n0 + wn * 64 + nf * 16 + lA;
      const float bv = bias[col];
#pragma unroll
      for (int q = 0; q < 4; ++q) {
        float v = gelu_fast(acc[mf][nf][q] + bv);
        Hs[(size_t)(rowbase + rloc + q) * H_DIM + col] = (bf16_t)(v * gr[q]);
      }
    }
  }
}

// ---------------------------------------------------------------- GEMM2 expert tiles: Ys(bf16) = acc + grow*b2[e]
__global__ __launch_bounds__(512, 2) void gemm2e_kernel(
    const bf16_t* __restrict__ Hs, const bf16_t* __restrict__ Bt2e,
    const float* __restrict__ grow, const int* __restrict__ padcnt,
    const float* __restrict__ b2, bf16_t* __restrict__ Ys) {
  __shared__ bf16_t sL[65536];
  const int t = threadIdx.x, wid = t >> 6, lane = t & 63;
  const int y = blockIdx.y;
  const int e = y / ET256;
  const int lt = y - e * ET256;
  if (lt * 256 >= padcnt[e]) return;
  const int rowbase = e * CAP + lt * 256;
  const int n0 = blockIdx.x * 256;       // N = 1024
  const int rl = wid * 8 + (lane >> 3);
  const int sc = swz_src(lane);
  const char *ga[4], *gb[4];
#pragma unroll
  for (int g = 0; g < 4; ++g) {
    const int r = g * 64 + rl;
    ga[g] = (const char*)Hs + (size_t)(rowbase + r) * 1024 + sc;
    gb[g] = (const char*)(Bt2e + (size_t)e * D_DIM * H_DIM) + (size_t)(n0 + r) * 1024 + sc;
  }
  f32x4 acc[8][4];
#pragma unroll
  for (int i = 0; i < 8; ++i)
#pragma unroll
    for (int j = 0; j < 4; ++j) acc[i][j] = (f32x4){0.f, 0.f, 0.f, 0.f};
  gemm_core256(ga[0], ga[1], ga[2], ga[3], gb[0], gb[1], gb[2], gb[3],
               H_DIM / 64, (char*)sL, wid, lane, acc);

  const int wm = wid >> 2, wn = wid & 3, lA = lane & 15;
  const float* bb = b2 + (size_t)e * D_DIM;
#pragma unroll
  for (int mf = 0; mf < 8; ++mf) {
    const int rloc = wm * 128 + mf * 16 + (lane >> 4) * 4;
    float gr[4];
#pragma unroll
    for (int q = 0; q < 4; ++q) gr[q] = grow[rowbase + rloc + q];
#pragma unroll
    for (int nf = 0; nf < 4; ++nf) {
      const int col = n0 + wn * 64 + nf * 16 + lA;
      const float bv = bb[col];
#pragma unroll
      for (int q = 0; q < 4; ++q)
        Ys[(size_t)(rowbase + rloc + q) * D_DIM + col] = (bf16_t)(acc[mf][nf][q] + gr[q] * bv);
    }
  }
}

// ---------------------------------------------------------------- GEMM2 shared tiles + combine
__global__ __launch_bounds__(512, 2) void gemm2s_kernel(
    const bf16_t* __restrict__ Hs, const bf16_t* __restrict__ Bt2e,
    const int* __restrict__ tok2row, const float* __restrict__ bs2,
    const bf16_t* __restrict__ Ys, float* __restrict__ out) {
  __shared__ bf16_t sL[65536];
  const int t = threadIdx.x, wid = t >> 6, lane = t & 63;
  const int tokbase = blockIdx.y * 256;
  const int rowbase = SH_BASE + tokbase;
  const int n0 = blockIdx.x * 256;       // N = 1024
  const int rl = wid * 8 + (lane >> 3);
  const int sc = swz_src(lane);
  const char *ga[4], *gb[4];
#pragma unroll
  for (int g = 0; g < 4; ++g) {
    const int r = g * 64 + rl;
    ga[g] = (const char*)Hs + (size_t)(rowbase + r) * 1024 + sc;
    gb[g] = (const char*)(Bt2e + (size_t)E_NUM * D_DIM * H_DIM) + (size_t)(n0 + r) * 1024 + sc;
  }
  f32x4 acc[8][4];
#pragma unroll
  for (int i = 0; i < 8; ++i)
#pragma unroll
    for (int j = 0; j < 4; ++j) acc[i][j] = (f32x4){0.f, 0.f, 0.f, 0.f};
  gemm_core256(ga[0], ga[1], ga[2], ga[3], gb[0], gb[1], gb[2], gb[3],
               H_DIM / 64, (char*)sL, wid, lane, acc);

  const int wm = wid >> 2, wn = wid & 3, lA = lane & 15;
#pragma unroll
  for (int mf = 0; mf < 8; ++mf) {
    const int rloc = wm * 128 + mf * 16 + (lane >> 4) * 4;
    int r0[4], r1[4];
#pragma unroll
    for (int q = 0; q < 4; ++q) {
      const int tok = tokbase + rloc + q;
      r0[q] = tok2row[tok * 2];
      r1[q] = tok2row[tok * 2 + 1];
    }
#pragma unroll
    for (int nf = 0; nf < 4; ++nf) {
      const int col = n0 + wn * 64 + nf * 16 + lA;
      const float bv = bs2[col];
#pragma unroll
      for (int q = 0; q < 4; ++q) {
        const int tok = tokbase + rloc + q;
        float y0 = (float)Ys[(size_t)r0[q] * D_DIM + col];
        float y1 = (float)Ys[(size_t)r1[q] * D_DIM + col];
        out[(size_t)tok * D_DIM + col] = acc[mf][nf][q] + bv + y0 + y1;
      }
    }
  }
}

// ---------------------------------------------------------------- launch
extern "C" void kernel_launch(void* const* d_in, const int* in_sizes, int n_in,
                              void* d_out, int out_size, void* d_ws, size_t ws_size,
                              hipStream_t stream) {
  (void)in_sizes; (void)n_in; (void)out_size; (void)ws_size;
  const float* x    = (const float*)d_in[0];
  const float* gW   = (const float*)d_in[1];
  const float* W1   = (const float*)d_in[2];
  const float* b1   = (const float*)d_in[3];
  const float* W2   = (const float*)d_in[4];
  const float* b2   = (const float*)d_in[5];
  const float* Ws1  = (const float*)d_in[6];
  const float* bs1  = (const float*)d_in[7];
  const float* Ws2  = (const float*)d_in[8];
  const float* bs2  = (const float*)d_in[9];
  const float* rsc  = (const float*)d_in[10];
  float* out = (float*)d_out;

  char* w = (char*)d_ws;
  float*  gateT = (float*)w;  w += (size_t)E_NUM * TOKENS * 4;       // 0.25 MB
  int*    sel   = (int*)w;    w += (size_t)TOKENS * 4;               // 32 KB
  bf16_t* Xb    = (bf16_t*)w; w += (size_t)TOKENS * D_DIM * 2;       // 16.8 MB
  bf16_t* Bt1   = (bf16_t*)w; w += (size_t)N1 * D_DIM * 2;           // 9.4 MB
  bf16_t* Bt2e  = (bf16_t*)w; w += (size_t)9 * D_DIM * H_DIM * 2;    // 9.4 MB
  bf16_t* Hs    = (bf16_t*)w; w += (size_t)HS_ROWS * H_DIM * 2;      // 33.6 MB
  bf16_t* Ys    = (bf16_t*)w; w += (size_t)EXP_ROWS * D_DIM * 2;     // 50.3 MB
  int*    perm  = (int*)w;    w += (size_t)EXP_ROWS * 4;             // 98 KB
  float*  grow  = (float*)w;  w += (size_t)EXP_ROWS * 4;             // 98 KB
  int*    tok2row = (int*)w;  w += (size_t)TOKENS * 2 * 4;           // 64 KB
  int*    padcnt  = (int*)w;                                         // 32 B

  routing_kernel<<<TOKENS / 4, 256, 0, stream>>>(x, gW, rsc, gateT, sel, Xb);
  listbuild_kernel<<<E_NUM, 256, 0, stream>>>(gateT, sel, perm, grow, tok2row, padcnt);
  repack1_kernel<<<dim3(D_DIM / 32, N1 / 32), dim3(32, 8), 0, stream>>>(W1, Ws1, Bt1);
  repack2e_kernel<<<dim3(D_DIM / 32, H_DIM / 32, 9), dim3(32, 8), 0, stream>>>(W2, Ws2, Bt2e);

  gemm1e_kernel<<<dim3(H_DIM / 256, E_NUM * ET256 + TOKENS / 256), dim3(512), 0, stream>>>(
      Xb, Bt1, perm, grow, padcnt, b1, bs1, Hs);
  gemm2e_kernel<<<dim3(D_DIM / 256, E_NUM * ET256), dim3(512), 0, stream>>>(
      Hs, Bt2e, grow, padcnt, b2, Ys);
  gemm2s_kernel<<<dim3(D_DIM / 256, TOKENS / 256), dim3(512), 0, stream>>>(
      Hs, Bt2e, tok2row, bs2, Ys, out);
}